// Round 4
// baseline (585.216 us; speedup 1.0000x reference)
//
#include <hip/hip_runtime.h>

// MoE router (BaseRouter): B=2,S=2048,H=2048,E=8,K=2,cap_factor=1.5
#define HID   2048
#define NE    8
#define NK    2
#define NTOK  4096              // B*S
#define NASS  (NTOK * NK)       // 8192 assignments
#define CAP   1536              // int(T*1.5*K/E)
#define DISP_ELEMS ((size_t)NTOK * NE * CAP)   // 50331648 floats per tensor
#define KBLK  (HID / 32)        // 64 k-blocks of 32 fp32 elements

typedef __bf16 bf16x8 __attribute__((ext_vector_type(8)));
typedef float  f32x4  __attribute__((ext_vector_type(4)));

typedef const __attribute__((address_space(1))) unsigned int GUint;
typedef       __attribute__((address_space(3))) unsigned int LUint;

__device__ __forceinline__ void gload16(const void* g, void* l) {
    // async global->LDS, 16B/lane; LDS dest = wave-uniform base + lane*16
    __builtin_amdgcn_global_load_lds((GUint*)g, (LUint*)l, 16, 0, 0);
}

// ---------------------------------------------------------------------------
// K0: fp32 -> split bf16 hi/lo, layout [row][KBLK][32hi|32lo]  (128B per blk)
// ---------------------------------------------------------------------------
__global__ __launch_bounds__(256) void split_kernel(
    const float* __restrict__ src, __bf16* __restrict__ dst, int nblk)
{
    int g = blockIdx.x * 256 + threadIdx.x;           // one 8-element group
    if (g >= nblk * 4) return;
    int blk = g >> 2, sub = g & 3;
    const float* s = src + (size_t)blk * 32 + sub * 8;
    float x[8];
    float4 v0 = ((const float4*)s)[0], v1 = ((const float4*)s)[1];
    x[0]=v0.x; x[1]=v0.y; x[2]=v0.z; x[3]=v0.w;
    x[4]=v1.x; x[5]=v1.y; x[6]=v1.z; x[7]=v1.w;
    bf16x8 h8, l8;
#pragma unroll
    for (int j = 0; j < 8; ++j) {
        __bf16 h = (__bf16)x[j];
        h8[j] = h;
        l8[j] = (__bf16)(x[j] - (float)h);
    }
    __bf16* d = dst + (size_t)blk * 64;
    *(bf16x8*)(d + sub * 8)      = h8;
    *(bf16x8*)(d + 32 + sub * 8) = l8;
}

// ---------------------------------------------------------------------------
// K1: h = relu(X @ W1^T + b1) via bf16x3-split MFMA (fp32-class accuracy).
// 128x128 tile, BK=32, 4 waves, 64x64/wave, double-buffered LDS staged with
// global_load_lds(16B), XOR-swizzled source so ds_read_b128 is conflict-free.
// ---------------------------------------------------------------------------
__global__ __launch_bounds__(256, 2) void gemm1_mfma_kernel(
    const __bf16* __restrict__ Xs,   // [4096][KBLK][64]
    const __bf16* __restrict__ Ws,   // [2048][KBLK][64]
    const float* __restrict__ b1, float* __restrict__ hout)
{
    __shared__ __bf16 As[2][128 * 64];
    __shared__ __bf16 Bs[2][128 * 64];

    const int tid  = threadIdx.x;
    const int wid  = tid >> 6;
    const int lane = tid & 63;

    // bijective XCD swizzle (512 blocks, 512%8==0)
    int wg  = blockIdx.x;
    int swz = (wg & 7) * 64 + (wg >> 3);
    const int bx = swz & 15;          // N panel (2048/128 = 16)
    const int by = swz >> 4;          // M panel (4096/128 = 32)
    const int brow = by * 128;
    const int bcol = bx * 128;

    const int srow   = lane >> 3;     // 0..7
    const int sslot  = lane & 7;      // LDS 16B slot within 128B row

    const int wr = wid >> 1, wc = wid & 1;   // wave's 64x64 quadrant
    const int fr = lane & 15;                // frag row/col
    const int fc = lane >> 4;                // k-chunk 0..3 (8 bf16 each)

    f32x4 acc[4][4];
#pragma unroll
    for (int m = 0; m < 4; ++m)
#pragma unroll
        for (int n = 0; n < 4; ++n) acc[m][n] = (f32x4)0.f;

#define STAGE(buf, b)                                                          \
    {                                                                          \
        _Pragma("unroll")                                                      \
        for (int i = 0; i < 4; ++i) {                                          \
            int ra = wid * 32 + i * 8 + srow;                                  \
            int ca = sslot ^ (ra & 7);                                         \
            gload16(Xs + ((size_t)(brow + ra) * KBLK + (b)) * 64 + ca * 8,     \
                    &As[buf][(wid * 32 + i * 8) * 64]);                        \
            int rb = wid * 32 + i * 8 + srow;                                  \
            int cb = sslot ^ (rb & 7);                                         \
            gload16(Ws + ((size_t)(bcol + rb) * KBLK + (b)) * 64 + cb * 8,     \
                    &Bs[buf][(wid * 32 + i * 8) * 64]);                        \
        }                                                                      \
    }

    int cur = 0;
    STAGE(0, 0);
    __syncthreads();

    for (int b = 0; b < KBLK; ++b) {
        if (b + 1 < KBLK) STAGE(cur ^ 1, b + 1);

        bf16x8 ah[4], al[4], bh[4], bl[4];
#pragma unroll
        for (int m = 0; m < 4; ++m) {
            int ra = wr * 64 + m * 16 + fr;
            ah[m] = *(const bf16x8*)&As[cur][ra * 64 + ((fc       ^ (ra & 7)) << 3)];
            al[m] = *(const bf16x8*)&As[cur][ra * 64 + (((4 + fc) ^ (ra & 7)) << 3)];
        }
#pragma unroll
        for (int n = 0; n < 4; ++n) {
            int rb = wc * 64 + n * 16 + fr;
            bh[n] = *(const bf16x8*)&Bs[cur][rb * 64 + ((fc       ^ (rb & 7)) << 3)];
            bl[n] = *(const bf16x8*)&Bs[cur][rb * 64 + (((4 + fc) ^ (rb & 7)) << 3)];
        }

#pragma unroll
        for (int m = 0; m < 4; ++m)
#pragma unroll
            for (int n = 0; n < 4; ++n) {
                f32x4 c = acc[m][n];
                c = __builtin_amdgcn_mfma_f32_16x16x32_bf16(ah[m], bh[n], c, 0, 0, 0);
                c = __builtin_amdgcn_mfma_f32_16x16x32_bf16(al[m], bh[n], c, 0, 0, 0);
                c = __builtin_amdgcn_mfma_f32_16x16x32_bf16(ah[m], bl[n], c, 0, 0, 0);
                acc[m][n] = c;
            }

        __syncthreads();
        cur ^= 1;
    }

    // epilogue: C/D frag layout (m89): col = lane&15, row = (lane>>4)*4 + reg
#pragma unroll
    for (int m = 0; m < 4; ++m) {
#pragma unroll
        for (int n = 0; n < 4; ++n) {
            int row = brow + wr * 64 + m * 16 + fc * 4;
            int col = bcol + wc * 64 + n * 16 + fr;
            float bias = b1[col];
#pragma unroll
            for (int j = 0; j < 4; ++j) {
                float v = acc[m][n][j] + bias;
                hout[(size_t)(row + j) * HID + col] = fmaxf(v, 0.f);
            }
        }
    }
#undef STAGE
}

// ---------------------------------------------------------------------------
// K2: wave-per-token router: coalesced float4 loads, butterfly shfl reduce,
// lane-0 softmax/top-2. w2 (64KB) stays L1/L2-resident.
// ---------------------------------------------------------------------------
__global__ __launch_bounds__(256) void router_kernel(
    const float* __restrict__ hbuf, const float* __restrict__ w2,
    const float* __restrict__ b2, float* __restrict__ probs_out,
    int* __restrict__ topk_e, float* __restrict__ topk_p)
{
    const int t    = (blockIdx.x * 256 + threadIdx.x) >> 6;   // token = wave
    const int lane = threadIdx.x & 63;
    const float* hrow = hbuf + (size_t)t * HID;

    float acc[NE];
#pragma unroll
    for (int e = 0; e < NE; ++e) acc[e] = 0.f;

#pragma unroll
    for (int j = 0; j < HID / (64 * 4); ++j) {              // 8 iters
        const int o = (j * 64 + lane) * 4;
        float4 hv = *(const float4*)(hrow + o);
#pragma unroll
        for (int e = 0; e < NE; ++e) {
            float4 wv = *(const float4*)(w2 + e * HID + o);
            acc[e] += hv.x * wv.x + hv.y * wv.y + hv.z * wv.z + hv.w * wv.w;
        }
    }
    // butterfly reduce across the 64-lane wave; all lanes end with full sums
#pragma unroll
    for (int m = 32; m > 0; m >>= 1)
#pragma unroll
        for (int e = 0; e < NE; ++e) acc[e] += __shfl_xor(acc[e], m);

    if (lane == 0) {
        float lg[NE];
        float mx = -1e30f;
#pragma unroll
        for (int e = 0; e < NE; ++e) { lg[e] = acc[e] + b2[e]; mx = fmaxf(mx, lg[e]); }
        float sum = 0.f;
#pragma unroll
        for (int e = 0; e < NE; ++e) { lg[e] = expf(lg[e] - mx); sum += lg[e]; }
        float inv = 1.f / sum;
        float p[NE];
#pragma unroll
        for (int e = 0; e < NE; ++e) { p[e] = lg[e] * inv; probs_out[t * NE + e] = p[e]; }
        // top-2, strict '>' keeps lowest index on ties (matches jax.lax.top_k)
        int e1 = 0;
#pragma unroll
        for (int e = 1; e < NE; ++e) if (p[e] > p[e1]) e1 = e;
        int e2 = -1;
#pragma unroll
        for (int e = 0; e < NE; ++e) if (e != e1 && (e2 < 0 || p[e] > p[e2])) e2 = e;
        float denom = p[e1] + p[e2] + 1e-8f;
        topk_e[t * NK + 0] = e1;
        topk_e[t * NK + 1] = e2;
        topk_p[t * NK + 0] = p[e1] / denom;
        topk_p[t * NK + 1] = p[e2] / denom;
    }
}

// ---------------------------------------------------------------------------
// K3: exact sequential-order capacity slots (cumsum per expert in (b,s,k)).
// ---------------------------------------------------------------------------
__global__ __launch_bounds__(256) void positions_kernel(
    const int* __restrict__ topk_e, int* __restrict__ pos)
{
    const int tid = threadIdx.x;
    __shared__ int sc[256][NE];
    int cnt[NE];
#pragma unroll
    for (int e = 0; e < NE; ++e) cnt[e] = 0;
    const int base = tid * 32;
    for (int i = 0; i < 32; ++i) cnt[topk_e[base + i]]++;
#pragma unroll
    for (int e = 0; e < NE; ++e) sc[tid][e] = cnt[e];
    __syncthreads();
    if (tid < NE) {
        int run = 0;
        for (int i = 0; i < 256; ++i) { int v = sc[i][tid]; sc[i][tid] = run; run += v; }
    }
    __syncthreads();
    int run[NE];
#pragma unroll
    for (int e = 0; e < NE; ++e) run[e] = sc[tid][e];
    for (int i = 0; i < 32; ++i) {
        int e = topk_e[base + i];
        pos[base + i] = run[e]++;
    }
}

// ---------------------------------------------------------------------------
// K4: zero-fill dispatch+combine (exactly 402MB, 16B nontemporal stores).
// Replaces rocclr fillBufferAligned (254us measured, ~4x write amplification).
// ---------------------------------------------------------------------------
__global__ __launch_bounds__(256) void zerofill_kernel(float* __restrict__ dst)
{
    const size_t n4 = 2 * DISP_ELEMS / 4;       // 25,165,824 16B chunks
    const size_t stride = (size_t)gridDim.x * 256;
    f32x4 z = (f32x4)0.f;
    f32x4* __restrict__ d = (f32x4*)dst;
    for (size_t i = blockIdx.x * 256 + threadIdx.x; i < n4; i += stride)
        __builtin_nontemporal_store(z, d + i);
}

// ---------------------------------------------------------------------------
// K5: scatter into zeroed dispatch/combine.
// ---------------------------------------------------------------------------
__global__ __launch_bounds__(256) void scatter_kernel(
    const int* __restrict__ topk_e, const float* __restrict__ topk_p,
    const int* __restrict__ pos, float* __restrict__ dispatch,
    float* __restrict__ combine)
{
    const int a = blockIdx.x * 256 + threadIdx.x;
    if (a >= NASS) return;
    const int p = pos[a];
    if (p < CAP) {
        const int t = a >> 1;
        const int e = topk_e[a];
        const size_t off = ((size_t)t * NE + e) * CAP + p;
        dispatch[off] = 1.0f;
        combine[off]  = topk_p[a];
    }
}

// ---------------------------------------------------------------------------
// K6: aux loss
// ---------------------------------------------------------------------------
__global__ __launch_bounds__(256) void aux_kernel(
    const float* __restrict__ probs, const int* __restrict__ topk_e,
    float* __restrict__ aux_out)
{
    const int tid = threadIdx.x;
    float ps[NE];
    int   cs[NE];
#pragma unroll
    for (int e = 0; e < NE; ++e) { ps[e] = 0.f; cs[e] = 0; }
    for (int t = tid; t < NTOK; t += 256)
#pragma unroll
        for (int e = 0; e < NE; ++e) ps[e] += probs[t * NE + e];
    for (int a = tid; a < NASS; a += 256) cs[topk_e[a]]++;

    __shared__ float rps[256][NE];
    __shared__ int   rcs[256][NE];
#pragma unroll
    for (int e = 0; e < NE; ++e) { rps[tid][e] = ps[e]; rcs[tid][e] = cs[e]; }
    __syncthreads();
    for (int s = 128; s > 0; s >>= 1) {
        if (tid < s) {
#pragma unroll
            for (int e = 0; e < NE; ++e) {
                rps[tid][e] += rps[tid + s][e];
                rcs[tid][e] += rcs[tid + s][e];
            }
        }
        __syncthreads();
    }
    if (tid == 0) {
        float aux = 0.f;
#pragma unroll
        for (int e = 0; e < NE; ++e)
            aux += (rps[0][e] / (float)NTOK) * ((float)rcs[0][e] / (float)NASS);
        aux_out[0] = aux * (float)NE;
    }
}

// ---------------------------------------------------------------------------
extern "C" void kernel_launch(void* const* d_in, const int* in_sizes, int n_in,
                              void* d_out, int out_size, void* d_ws, size_t ws_size,
                              hipStream_t stream)
{
    const float* X  = (const float*)d_in[0];   // [2,2048,2048]
    const float* w1 = (const float*)d_in[1];   // [2048,2048]
    const float* b1 = (const float*)d_in[2];   // [2048]
    const float* w2 = (const float*)d_in[3];   // [8,2048]
    const float* b2 = (const float*)d_in[4];   // [8]

    float* out      = (float*)d_out;
    float* dispatch = out;                                   // [T,E,CAP]
    float* combine  = out + DISP_ELEMS;                      // [T,E,CAP]
    float* probs    = out + 2 * DISP_ELEMS;                  // [T,E]
    float* aux      = out + 2 * DISP_ELEMS + (size_t)NTOK * NE;

    // Scratch staged INSIDE the dispatch region of d_out (wiped by zerofill
    // after consumption): hbuf (33.5MB) + Xs (33.5MB) + Ws (16.8MB) << 201MB.
    float*  hbuf = dispatch;
    __bf16* Xs   = (__bf16*)(dispatch + (size_t)NTOK * HID);
    __bf16* Ws   = Xs + (size_t)NTOK * HID * 2;

    int*   topk_e = (int*)d_ws;                       // 8192 ints
    int*   pos    = (int*)d_ws + NASS;                // 8192 ints
    float* topk_p = (float*)((int*)d_ws + 2 * NASS);  // 8192 floats

    split_kernel<<<(NTOK * KBLK * 4 + 255) / 256, 256, 0, stream>>>(X,  Xs, NTOK * KBLK);
    split_kernel<<<(HID  * KBLK * 4 + 255) / 256, 256, 0, stream>>>(w1, Ws, HID * KBLK);
    gemm1_mfma_kernel<<<512, 256, 0, stream>>>(Xs, Ws, b1, hbuf);
    router_kernel<<<NTOK / 4, 256, 0, stream>>>(hbuf, w2, b2, probs, topk_e, topk_p);
    positions_kernel<<<1, 256, 0, stream>>>(topk_e, pos);
    zerofill_kernel<<<2048, 256, 0, stream>>>(out);
    scatter_kernel<<<(NASS + 255) / 256, 256, 0, stream>>>(topk_e, topk_p, pos, dispatch, combine);
    aux_kernel<<<1, 256, 0, stream>>>(probs, topk_e, aux);
}

// Round 5
// 506.004 us; speedup vs baseline: 1.1565x; 1.1565x over previous
//
#include <hip/hip_runtime.h>

// MoE router (BaseRouter): B=2,S=2048,H=2048,E=8,K=2,cap_factor=1.5
#define HID   2048
#define NE    8
#define NK    2
#define NTOK  4096              // B*S
#define NASS  (NTOK * NK)       // 8192 assignments
#define CAP   1536              // int(T*1.5*K/E)
#define DISP_ELEMS ((size_t)NTOK * NE * CAP)   // 50331648 floats per tensor
#define KBLK  (HID / 32)        // 64 k-blocks of 32 fp32 elements
#define ZCHUNKS_PER_BLK 49152   // (2*DISP_ELEMS/4) / 512 blocks, 16B chunks

typedef __bf16 bf16x8 __attribute__((ext_vector_type(8)));
typedef float  f32x4  __attribute__((ext_vector_type(4)));

typedef const __attribute__((address_space(1))) unsigned int GUint;
typedef       __attribute__((address_space(3))) unsigned int LUint;

__device__ __forceinline__ void gload16(const void* g, void* l) {
    __builtin_amdgcn_global_load_lds((GUint*)g, (LUint*)l, 16, 0, 0);
}

// ---------------------------------------------------------------------------
// K0: fp32 -> split bf16 hi/lo, layout [row][KBLK][32hi|32lo]  (128B per blk)
// ---------------------------------------------------------------------------
__global__ __launch_bounds__(256) void split_kernel(
    const float* __restrict__ src, __bf16* __restrict__ dst, int nblk)
{
    int g = blockIdx.x * 256 + threadIdx.x;
    if (g >= nblk * 4) return;
    int blk = g >> 2, sub = g & 3;
    const float* s = src + (size_t)blk * 32 + sub * 8;
    float x[8];
    float4 v0 = ((const float4*)s)[0], v1 = ((const float4*)s)[1];
    x[0]=v0.x; x[1]=v0.y; x[2]=v0.z; x[3]=v0.w;
    x[4]=v1.x; x[5]=v1.y; x[6]=v1.z; x[7]=v1.w;
    bf16x8 h8, l8;
#pragma unroll
    for (int j = 0; j < 8; ++j) {
        __bf16 h = (__bf16)x[j];
        h8[j] = h;
        l8[j] = (__bf16)(x[j] - (float)h);
    }
    __bf16* d = dst + (size_t)blk * 64;
    *(bf16x8*)(d + sub * 8)      = h8;
    *(bf16x8*)(d + 32 + sub * 8) = l8;
}

// ---------------------------------------------------------------------------
// K1: h = relu(X @ W1^T + b1) via bf16x3-split MFMA + FUSED zero-fill of
// dispatch+combine (402MB): 3x16B NT stores per thread per K-iter, hidden
// under the MFMA loop (gemm is compute-bound, spare write BW is free).
// ---------------------------------------------------------------------------
__global__ __launch_bounds__(256, 2) void gemm1_mfma_kernel(
    const __bf16* __restrict__ Xs,   // [4096][KBLK][64]
    const __bf16* __restrict__ Ws,   // [2048][KBLK][64]
    const float* __restrict__ b1, float* __restrict__ hout,
    float* __restrict__ zout)        // d_out: 2*DISP_ELEMS floats to zero
{
    __shared__ __bf16 As[2][128 * 64];
    __shared__ __bf16 Bs[2][128 * 64];

    const int tid  = threadIdx.x;
    const int wid  = tid >> 6;
    const int lane = tid & 63;

    // bijective XCD swizzle (512 blocks, 512%8==0)
    int wg  = blockIdx.x;
    int swz = (wg & 7) * 64 + (wg >> 3);
    const int bx = swz & 15;          // N panel (2048/128 = 16)
    const int by = swz >> 4;          // M panel (4096/128 = 32)
    const int brow = by * 128;
    const int bcol = bx * 128;

    const int srow   = lane >> 3;
    const int sslot  = lane & 7;

    const int wr = wid >> 1, wc = wid & 1;
    const int fr = lane & 15;
    const int fc = lane >> 4;

    // fused-zero destination (raw blockIdx slice; ordering irrelevant)
    f32x4* zdst = (f32x4*)zout + (size_t)blockIdx.x * ZCHUNKS_PER_BLK + tid;
    const f32x4 zz = (f32x4)0.f;

    f32x4 acc[4][4];
#pragma unroll
    for (int m = 0; m < 4; ++m)
#pragma unroll
        for (int n = 0; n < 4; ++n) acc[m][n] = (f32x4)0.f;

#define STAGE(buf, b)                                                          \
    {                                                                          \
        _Pragma("unroll")                                                      \
        for (int i = 0; i < 4; ++i) {                                          \
            int ra = wid * 32 + i * 8 + srow;                                  \
            int ca = sslot ^ (ra & 7);                                         \
            gload16(Xs + ((size_t)(brow + ra) * KBLK + (b)) * 64 + ca * 8,     \
                    &As[buf][(wid * 32 + i * 8) * 64]);                        \
            int rb = wid * 32 + i * 8 + srow;                                  \
            int cb = sslot ^ (rb & 7);                                         \
            gload16(Ws + ((size_t)(bcol + rb) * KBLK + (b)) * 64 + cb * 8,     \
                    &Bs[buf][(wid * 32 + i * 8) * 64]);                        \
        }                                                                      \
    }

    int cur = 0;
    STAGE(0, 0);
    __syncthreads();

    for (int b = 0; b < KBLK; ++b) {
        if (b + 1 < KBLK) STAGE(cur ^ 1, b + 1);

        // fused zero-fill: 768 coalesced 16B chunks per block per iter
        {
            f32x4* z = zdst + (size_t)b * 768;
            __builtin_nontemporal_store(zz, z);
            __builtin_nontemporal_store(zz, z + 256);
            __builtin_nontemporal_store(zz, z + 512);
        }

        bf16x8 ah[4], al[4], bh[4], bl[4];
#pragma unroll
        for (int m = 0; m < 4; ++m) {
            int ra = wr * 64 + m * 16 + fr;
            ah[m] = *(const bf16x8*)&As[cur][ra * 64 + ((fc       ^ (ra & 7)) << 3)];
            al[m] = *(const bf16x8*)&As[cur][ra * 64 + (((4 + fc) ^ (ra & 7)) << 3)];
        }
#pragma unroll
        for (int n = 0; n < 4; ++n) {
            int rb = wc * 64 + n * 16 + fr;
            bh[n] = *(const bf16x8*)&Bs[cur][rb * 64 + ((fc       ^ (rb & 7)) << 3)];
            bl[n] = *(const bf16x8*)&Bs[cur][rb * 64 + (((4 + fc) ^ (rb & 7)) << 3)];
        }

#pragma unroll
        for (int m = 0; m < 4; ++m)
#pragma unroll
            for (int n = 0; n < 4; ++n) {
                f32x4 c = acc[m][n];
                c = __builtin_amdgcn_mfma_f32_16x16x32_bf16(ah[m], bh[n], c, 0, 0, 0);
                c = __builtin_amdgcn_mfma_f32_16x16x32_bf16(al[m], bh[n], c, 0, 0, 0);
                c = __builtin_amdgcn_mfma_f32_16x16x32_bf16(ah[m], bl[n], c, 0, 0, 0);
                acc[m][n] = c;
            }

        __syncthreads();
        cur ^= 1;
    }

    // epilogue: C/D frag layout (m89): col = lane&15, row = (lane>>4)*4 + reg
#pragma unroll
    for (int m = 0; m < 4; ++m) {
#pragma unroll
        for (int n = 0; n < 4; ++n) {
            int row = brow + wr * 64 + m * 16 + fc * 4;
            int col = bcol + wc * 64 + n * 16 + fr;
            float bias = b1[col];
#pragma unroll
            for (int j = 0; j < 4; ++j) {
                float v = acc[m][n][j] + bias;
                hout[(size_t)(row + j) * HID + col] = fmaxf(v, 0.f);
            }
        }
    }
#undef STAGE
}

// ---------------------------------------------------------------------------
// K2: wave-per-token router: coalesced float4 loads, butterfly shfl reduce,
// lane-0 softmax/top-2. w2 (64KB) stays L1/L2-resident.
// ---------------------------------------------------------------------------
__global__ __launch_bounds__(256) void router_kernel(
    const float* __restrict__ hbuf, const float* __restrict__ w2,
    const float* __restrict__ b2, float* __restrict__ probs_out,
    int* __restrict__ topk_e, float* __restrict__ topk_p)
{
    const int t    = (blockIdx.x * 256 + threadIdx.x) >> 6;
    const int lane = threadIdx.x & 63;
    const float* hrow = hbuf + (size_t)t * HID;

    float acc[NE];
#pragma unroll
    for (int e = 0; e < NE; ++e) acc[e] = 0.f;

#pragma unroll
    for (int j = 0; j < HID / (64 * 4); ++j) {
        const int o = (j * 64 + lane) * 4;
        float4 hv = *(const float4*)(hrow + o);
#pragma unroll
        for (int e = 0; e < NE; ++e) {
            float4 wv = *(const float4*)(w2 + e * HID + o);
            acc[e] += hv.x * wv.x + hv.y * wv.y + hv.z * wv.z + hv.w * wv.w;
        }
    }
#pragma unroll
    for (int m = 32; m > 0; m >>= 1)
#pragma unroll
        for (int e = 0; e < NE; ++e) acc[e] += __shfl_xor(acc[e], m);

    if (lane == 0) {
        float lg[NE];
        float mx = -1e30f;
#pragma unroll
        for (int e = 0; e < NE; ++e) { lg[e] = acc[e] + b2[e]; mx = fmaxf(mx, lg[e]); }
        float sum = 0.f;
#pragma unroll
        for (int e = 0; e < NE; ++e) { lg[e] = expf(lg[e] - mx); sum += lg[e]; }
        float inv = 1.f / sum;
        float p[NE];
#pragma unroll
        for (int e = 0; e < NE; ++e) { p[e] = lg[e] * inv; probs_out[t * NE + e] = p[e]; }
        // top-2, strict '>' keeps lowest index on ties (matches jax.lax.top_k)
        int e1 = 0;
#pragma unroll
        for (int e = 1; e < NE; ++e) if (p[e] > p[e1]) e1 = e;
        int e2 = -1;
#pragma unroll
        for (int e = 0; e < NE; ++e) if (e != e1 && (e2 < 0 || p[e] > p[e2])) e2 = e;
        float denom = p[e1] + p[e2] + 1e-8f;
        topk_e[t * NK + 0] = e1;
        topk_e[t * NK + 1] = e2;
        topk_p[t * NK + 0] = p[e1] / denom;
        topk_p[t * NK + 1] = p[e2] / denom;
    }
}

// ---------------------------------------------------------------------------
// K3: fused positions+scatter+aux. One 256-thread block.
// Phase 1: per-expert exclusive scan over (b,s,k) order -> slot, scatter
//          writes directly (dispatch/combine already zeroed by gemm).
// Phase 2: aux loss from probs + pre-capacity expert counts.
// ---------------------------------------------------------------------------
__global__ __launch_bounds__(256) void finalize_kernel(
    const int* __restrict__ topk_e, const float* __restrict__ topk_p,
    const float* __restrict__ probs, float* __restrict__ dispatch,
    float* __restrict__ combine, float* __restrict__ aux_out)
{
    const int tid = threadIdx.x;
    __shared__ int   sc[256][NE];
    __shared__ float tot[NE];
    __shared__ float rps[256][NE];

    // phase 1: counts
    int cnt[NE];
#pragma unroll
    for (int e = 0; e < NE; ++e) cnt[e] = 0;
    const int base = tid * 32;
    int eloc[32];
    for (int i = 0; i < 32; ++i) { eloc[i] = topk_e[base + i]; cnt[eloc[i]]++; }
#pragma unroll
    for (int e = 0; e < NE; ++e) sc[tid][e] = cnt[e];
    __syncthreads();
    if (tid < NE) {                          // serial exclusive scan per expert
        int run = 0;
        for (int i = 0; i < 256; ++i) { int v = sc[i][tid]; sc[i][tid] = run; run += v; }
        tot[tid] = (float)run;               // pre-capacity total per expert
    }
    __syncthreads();
    int run[NE];
#pragma unroll
    for (int e = 0; e < NE; ++e) run[e] = sc[tid][e];
    for (int i = 0; i < 32; ++i) {
        const int a = base + i;
        const int e = eloc[i];
        const int p = run[e]++;
        if (p < CAP) {
            const int t = a >> 1;
            const size_t off = ((size_t)t * NE + e) * CAP + p;
            dispatch[off] = 1.0f;
            combine[off]  = topk_p[a];
        }
    }

    // phase 2: aux loss
    float ps[NE];
#pragma unroll
    for (int e = 0; e < NE; ++e) ps[e] = 0.f;
    for (int t = tid; t < NTOK; t += 256)
#pragma unroll
        for (int e = 0; e < NE; ++e) ps[e] += probs[t * NE + e];
#pragma unroll
    for (int e = 0; e < NE; ++e) rps[tid][e] = ps[e];
    __syncthreads();
    for (int s = 128; s > 0; s >>= 1) {
        if (tid < s) {
#pragma unroll
            for (int e = 0; e < NE; ++e) rps[tid][e] += rps[tid + s][e];
        }
        __syncthreads();
    }
    if (tid == 0) {
        float aux = 0.f;
#pragma unroll
        for (int e = 0; e < NE; ++e)
            aux += (rps[0][e] / (float)NTOK) * (tot[e] / (float)NASS);
        aux_out[0] = aux * (float)NE;
    }
}

// ---------------------------------------------------------------------------
extern "C" void kernel_launch(void* const* d_in, const int* in_sizes, int n_in,
                              void* d_out, int out_size, void* d_ws, size_t ws_size,
                              hipStream_t stream)
{
    const float* X  = (const float*)d_in[0];   // [2,2048,2048]
    const float* w1 = (const float*)d_in[1];   // [2048,2048]
    const float* b1 = (const float*)d_in[2];   // [2048]
    const float* w2 = (const float*)d_in[3];   // [8,2048]
    const float* b2 = (const float*)d_in[4];   // [8]

    float* out      = (float*)d_out;
    float* dispatch = out;                                   // [T,E,CAP]
    float* combine  = out + DISP_ELEMS;                      // [T,E,CAP]
    float* probs    = out + 2 * DISP_ELEMS;                  // [T,E]
    float* aux      = out + 2 * DISP_ELEMS + (size_t)NTOK * NE;

    // Scratch in d_ws (~84MB; ws arena is ~1.6GB per harness poison fills):
    __bf16* Xs     = (__bf16*)d_ws;                          // 16.8M bf16 = 33.5MB
    __bf16* Ws     = Xs + (size_t)NTOK * HID * 2;            // 8.4M bf16  = 16.8MB
    float*  hbuf   = (float*)(Ws + (size_t)HID * HID * 2);   // 33.5MB
    int*    topk_e = (int*)(hbuf + (size_t)NTOK * HID);      // 8192 ints
    float*  topk_p = (float*)(topk_e + NASS);                // 8192 floats

    split_kernel<<<(NTOK * KBLK * 4 + 255) / 256, 256, 0, stream>>>(X,  Xs, NTOK * KBLK);
    split_kernel<<<(HID  * KBLK * 4 + 255) / 256, 256, 0, stream>>>(w1, Ws, HID * KBLK);
    gemm1_mfma_kernel<<<512, 256, 0, stream>>>(Xs, Ws, b1, hbuf, out);
    router_kernel<<<NTOK / 4, 256, 0, stream>>>(hbuf, w2, b2, probs, topk_e, topk_p);
    finalize_kernel<<<1, 256, 0, stream>>>(topk_e, topk_p, probs, dispatch, combine, aux);
}